// Round 1
// baseline (2039.493 us; speedup 1.0000x reference)
//
#include <hip/hip_runtime.h>

// Problem constants
constexpr int Bb = 16;     // batch
constexpr int Nn = 256;    // regions
constexpr int Hh = 768;    // hidden
constexpr int Pp = 2048;   // proj dim
constexpr int Rr = 3;      // relation types
constexpr int Mm = Bb * Nn; // 4096 flattened rows

constexpr int TS = 64;   // output tile (TS x TS)
constexpr int KT = 16;   // K tile
constexpr int PAD = 4;   // LDS pad (keeps float4 alignment, breaks pow2 stride)

// ---------------------------------------------------------------------------
// proj: C[m,p] = sum_h F[m,h] * W[p,h] + bias[p]
// A [M,K] row-major, W [N,K] row-major (K fast on both) -> A * W^T
// blockIdx.z selects (head vs tail)
// ---------------------------------------------------------------------------
__global__ __launch_bounds__(256) void proj_kernel(
    const float* __restrict__ F,
    const float* __restrict__ Wh, const float* __restrict__ bh,
    const float* __restrict__ Wt, const float* __restrict__ bt,
    float* __restrict__ Chead, float* __restrict__ Ctail)
{
    const float* W; const float* bias; float* C;
    if (blockIdx.z == 0) { W = Wh; bias = bh; C = Chead; }
    else                 { W = Wt; bias = bt; C = Ctail; }

    __shared__ float As[KT][TS + PAD];
    __shared__ float Bs[KT][TS + PAD];

    const int tid = threadIdx.x;
    const int tx = tid & 15, ty = tid >> 4;
    const int n0 = blockIdx.x * TS;   // P tile
    const int m0 = blockIdx.y * TS;   // M tile

    const int lr = tid >> 2;          // 0..63 row within tile
    const int lk = (tid & 3) * 4;     // 0,4,8,12 k within tile

    float acc[4][4] = {};

    for (int k0 = 0; k0 < Hh; k0 += KT) {
        float4 av = *(const float4*)(F + (size_t)(m0 + lr) * Hh + k0 + lk);
        float4 bv = *(const float4*)(W + (size_t)(n0 + lr) * Hh + k0 + lk);
        As[lk + 0][lr] = av.x; As[lk + 1][lr] = av.y;
        As[lk + 2][lr] = av.z; As[lk + 3][lr] = av.w;
        Bs[lk + 0][lr] = bv.x; Bs[lk + 1][lr] = bv.y;
        Bs[lk + 2][lr] = bv.z; Bs[lk + 3][lr] = bv.w;
        __syncthreads();
        #pragma unroll
        for (int k = 0; k < KT; ++k) {
            float4 a4 = *(const float4*)&As[k][ty * 4];
            float4 b4 = *(const float4*)&Bs[k][tx * 4];
            float a[4] = {a4.x, a4.y, a4.z, a4.w};
            float b[4] = {b4.x, b4.y, b4.z, b4.w};
            #pragma unroll
            for (int i = 0; i < 4; ++i)
                #pragma unroll
                for (int j = 0; j < 4; ++j)
                    acc[i][j] = fmaf(a[i], b[j], acc[i][j]);
        }
        __syncthreads();
    }

    #pragma unroll
    for (int i = 0; i < 4; ++i) {
        const int m = m0 + ty * 4 + i;
        #pragma unroll
        for (int j = 0; j < 4; ++j) {
            const int n = n0 + tx * 4 + j;
            C[(size_t)m * Pp + n] = acc[i][j] + bias[n];
        }
    }
}

// ---------------------------------------------------------------------------
// hw: C[m,q] = sum_p A[m,p] * B[p,q]   (A [M,P] row, B [P,Q] row, NN-GEMM)
// ---------------------------------------------------------------------------
__global__ __launch_bounds__(256) void gemm_nn_kernel(
    const float* __restrict__ A,   // [Mm, Pp]
    const float* __restrict__ B,   // [Pp, Pp] = bil_W[r]
    float* __restrict__ C)         // [Mm, Pp]
{
    __shared__ float As[KT][TS + PAD];
    __shared__ float Bs[KT][TS + PAD];

    const int tid = threadIdx.x;
    const int tx = tid & 15, ty = tid >> 4;
    const int n0 = blockIdx.x * TS;   // Q tile
    const int m0 = blockIdx.y * TS;   // M tile

    const int lr = tid >> 2;          // A-load: row in tile
    const int lk = (tid & 3) * 4;     // A-load: k in tile
    const int br = tid >> 4;          // B-load: k row 0..15
    const int bc = (tid & 15) * 4;    // B-load: col

    float acc[4][4] = {};

    for (int k0 = 0; k0 < Pp; k0 += KT) {
        float4 av = *(const float4*)(A + (size_t)(m0 + lr) * Pp + k0 + lk);
        float4 bv = *(const float4*)(B + (size_t)(k0 + br) * Pp + n0 + bc);
        As[lk + 0][lr] = av.x; As[lk + 1][lr] = av.y;
        As[lk + 2][lr] = av.z; As[lk + 3][lr] = av.w;
        *(float4*)&Bs[br][bc] = bv;
        __syncthreads();
        #pragma unroll
        for (int k = 0; k < KT; ++k) {
            float4 a4 = *(const float4*)&As[k][ty * 4];
            float4 b4 = *(const float4*)&Bs[k][tx * 4];
            float a[4] = {a4.x, a4.y, a4.z, a4.w};
            float b[4] = {b4.x, b4.y, b4.z, b4.w};
            #pragma unroll
            for (int i = 0; i < 4; ++i)
                #pragma unroll
                for (int j = 0; j < 4; ++j)
                    acc[i][j] = fmaf(a[i], b[j], acc[i][j]);
        }
        __syncthreads();
    }

    #pragma unroll
    for (int i = 0; i < 4; ++i) {
        const int m = m0 + ty * 4 + i;
        #pragma unroll
        for (int j = 0; j < 4; ++j) {
            C[(size_t)m * Pp + n0 + tx * 4 + j] = acc[i][j];
        }
    }
}

// ---------------------------------------------------------------------------
// out: logits[b,n,m,r] = sum_q HW[b*Nn+n, q] * TAIL[b*Nn+m, q] + bil_b[r]
// per-batch NT-GEMM 256x256x2048, strided output write (stride Rr on m)
// ---------------------------------------------------------------------------
__global__ __launch_bounds__(256) void gemm_out_kernel(
    const float* __restrict__ HW,    // [Mm, Pp] for this r
    const float* __restrict__ TAIL,  // [Mm, Pp]
    const float* __restrict__ bil_b, // [Rr]
    float* __restrict__ OUT,         // [Bb, Nn, Nn, Rr]
    int r)
{
    const int b = blockIdx.z;
    const float* A = HW   + (size_t)b * Nn * Pp;   // rows n
    const float* Bt = TAIL + (size_t)b * Nn * Pp;  // rows m

    __shared__ float As[KT][TS + PAD];
    __shared__ float Bs[KT][TS + PAD];

    const int tid = threadIdx.x;
    const int tx = tid & 15, ty = tid >> 4;
    const int n0 = blockIdx.y * TS;   // n tile (rows)
    const int m0 = blockIdx.x * TS;   // m tile (cols)

    const int lr = tid >> 2;
    const int lk = (tid & 3) * 4;

    float acc[4][4] = {};

    for (int k0 = 0; k0 < Pp; k0 += KT) {
        float4 av = *(const float4*)(A  + (size_t)(n0 + lr) * Pp + k0 + lk);
        float4 bv = *(const float4*)(Bt + (size_t)(m0 + lr) * Pp + k0 + lk);
        As[lk + 0][lr] = av.x; As[lk + 1][lr] = av.y;
        As[lk + 2][lr] = av.z; As[lk + 3][lr] = av.w;
        Bs[lk + 0][lr] = bv.x; Bs[lk + 1][lr] = bv.y;
        Bs[lk + 2][lr] = bv.z; Bs[lk + 3][lr] = bv.w;
        __syncthreads();
        #pragma unroll
        for (int k = 0; k < KT; ++k) {
            float4 a4 = *(const float4*)&As[k][ty * 4];
            float4 b4 = *(const float4*)&Bs[k][tx * 4];
            float a[4] = {a4.x, a4.y, a4.z, a4.w};
            float b[4] = {b4.x, b4.y, b4.z, b4.w};
            #pragma unroll
            for (int i = 0; i < 4; ++i)
                #pragma unroll
                for (int j = 0; j < 4; ++j)
                    acc[i][j] = fmaf(a[i], b[j], acc[i][j]);
        }
        __syncthreads();
    }

    const float bias = bil_b[r];
    #pragma unroll
    for (int i = 0; i < 4; ++i) {
        const int n = n0 + ty * 4 + i;
        #pragma unroll
        for (int j = 0; j < 4; ++j) {
            const int m = m0 + tx * 4 + j;
            OUT[(((size_t)b * Nn + n) * Nn + m) * Rr + r] = acc[i][j] + bias;
        }
    }
}

extern "C" void kernel_launch(void* const* d_in, const int* in_sizes, int n_in,
                              void* d_out, int out_size, void* d_ws, size_t ws_size,
                              hipStream_t stream) {
    const float* features = (const float*)d_in[0]; // [16,256,768]
    const float* head_W   = (const float*)d_in[1]; // [2048,768]
    const float* head_b   = (const float*)d_in[2]; // [2048]
    const float* tail_W   = (const float*)d_in[3]; // [2048,768]
    const float* tail_b   = (const float*)d_in[4]; // [2048]
    const float* bil_W    = (const float*)d_in[5]; // [3,2048,2048]
    const float* bil_b    = (const float*)d_in[6]; // [3]
    float* out = (float*)d_out;                    // [16,256,256,3]

    // workspace: head[Mm*Pp] | tail[Mm*Pp] | hw[Mm*Pp]  = 100.7 MB fp32
    float* head_buf = (float*)d_ws;
    float* tail_buf = head_buf + (size_t)Mm * Pp;
    float* hw_buf   = tail_buf + (size_t)Mm * Pp;

    // 1) projections: head & tail
    {
        dim3 grid(Pp / TS, Mm / TS, 2);   // 32 x 64 x 2
        proj_kernel<<<grid, 256, 0, stream>>>(features, head_W, head_b,
                                              tail_W, tail_b, head_buf, tail_buf);
    }

    // 2) per relation r: hw = head @ bil_W[r]; logits[..,r] = hw_b @ tail_b^T + bil_b[r]
    for (int r = 0; r < Rr; ++r) {
        {
            dim3 grid(Pp / TS, Mm / TS, 1); // 32 x 64
            gemm_nn_kernel<<<grid, 256, 0, stream>>>(head_buf,
                                                     bil_W + (size_t)r * Pp * Pp,
                                                     hw_buf);
        }
        {
            dim3 grid(Nn / TS, Nn / TS, Bb); // 4 x 4 x 16
            gemm_out_kernel<<<grid, 256, 0, stream>>>(hw_buf, tail_buf, bil_b,
                                                      out, r);
        }
    }
}

// Round 2
// 376.975 us; speedup vs baseline: 5.4101x; 5.4101x over previous
//
#include <hip/hip_runtime.h>

// Problem constants
constexpr int Bb = 16;      // batch
constexpr int Nn = 256;     // regions
constexpr int Hh = 768;     // hidden
constexpr int Pp = 2048;    // proj dim
constexpr int Rr = 3;       // relation types
constexpr int Mm = Bb * Nn; // 4096 flattened rows

typedef __bf16 bf16_t;
typedef __bf16 bf16x8 __attribute__((ext_vector_type(8)));
typedef __bf16 bf16x4 __attribute__((ext_vector_type(4)));
typedef float  floatx4 __attribute__((ext_vector_type(4)));

// async global->LDS, 16B per lane; LDS dest = wave-uniform base + lane*16
__device__ __forceinline__ void gld_lds16(const void* g, void* l) {
    __builtin_amdgcn_global_load_lds(
        (__attribute__((address_space(1))) void*)g,
        (__attribute__((address_space(3))) void*)l,
        16, 0, 0);
}

// ---------------------------------------------------------------------------
// convert features / head_W / tail_W to bf16 (elementwise, float4-vectorized)
// ---------------------------------------------------------------------------
__global__ __launch_bounds__(256) void convert_kernel(
    const float* __restrict__ f,  const float* __restrict__ hW, const float* __restrict__ tW,
    bf16_t* __restrict__ fo, bf16_t* __restrict__ hWo, bf16_t* __restrict__ tWo)
{
    const int i = blockIdx.x * 256 + threadIdx.x;
    if (i < Mm * Hh / 4) {
        float4 v = ((const float4*)f)[i];
        bf16x4 o = { (bf16_t)v.x, (bf16_t)v.y, (bf16_t)v.z, (bf16_t)v.w };
        *(bf16x4*)(fo + (size_t)i * 4) = o;
    }
    if (i < Pp * Hh / 4) {
        float4 v = ((const float4*)hW)[i];
        bf16x4 o = { (bf16_t)v.x, (bf16_t)v.y, (bf16_t)v.z, (bf16_t)v.w };
        *(bf16x4*)(hWo + (size_t)i * 4) = o;
        float4 w = ((const float4*)tW)[i];
        bf16x4 p = { (bf16_t)w.x, (bf16_t)w.y, (bf16_t)w.z, (bf16_t)w.w };
        *(bf16x4*)(tWo + (size_t)i * 4) = p;
    }
}

// ---------------------------------------------------------------------------
// bil_W [r][p][q] fp32  ->  bilT [r][q][p] bf16  (32x32 LDS-tiled transpose)
// ---------------------------------------------------------------------------
__global__ __launch_bounds__(256) void transpose_bilW_kernel(
    const float* __restrict__ W, bf16_t* __restrict__ Wt)
{
    __shared__ float t[32][33];
    const int r  = blockIdx.z;
    const int p0 = blockIdx.y * 32;
    const int q0 = blockIdx.x * 32;
    const int tx = threadIdx.x, ty = threadIdx.y; // 32 x 8
    const float* src = W  + (size_t)r * Pp * Pp;
    bf16_t*      dst = Wt + (size_t)r * Pp * Pp;
    #pragma unroll
    for (int s = 0; s < 4; ++s)
        t[ty + s * 8][tx] = src[(size_t)(p0 + ty + s * 8) * Pp + q0 + tx];
    __syncthreads();
    #pragma unroll
    for (int s = 0; s < 4; ++s)
        dst[(size_t)(q0 + ty + s * 8) * Pp + p0 + tx] = (bf16_t)t[tx][ty + s * 8];
}

// ---------------------------------------------------------------------------
// 128x128-tile bf16 NT GEMM (m97 structure):
//   C[m,n] = sum_k A[m,k]*B[n,k] (+ bias[n]),  C stored bf16
// 256 threads = 4 waves (2x2), each wave 64x64 = 4x4 MFMA 16x16x32 tiles.
// ---------------------------------------------------------------------------
template <int K, bool ADD_BIAS>
__global__ __launch_bounds__(256) void gemm_nt_128(
    const bf16_t* __restrict__ A,   // [gridDim.y*128, K]
    const bf16_t* __restrict__ B,   // [gridDim.x*128, K]
    const float*  __restrict__ bias,
    bf16_t* __restrict__ C, int ldc)
{
    __shared__ bf16_t As[128 * 32];
    __shared__ bf16_t Bs[128 * 32];

    const int tid = threadIdx.x;
    const int w = tid >> 6;
    const int l = tid & 63;
    const int m0 = blockIdx.y * 128;
    const int n0 = blockIdx.x * 128;

    // staging: each thread loads 16B; wave w covers rows w*16 + l/4 (per 64-row half)
    const int srow = (w << 4) + (l >> 2);
    const int scol = (l & 3) << 3;
    const bf16_t* ga0 = A + (size_t)(m0 +      srow) * K + scol;
    const bf16_t* ga1 = A + (size_t)(m0 + 64 + srow) * K + scol;
    const bf16_t* gb0 = B + (size_t)(n0 +      srow) * K + scol;
    const bf16_t* gb1 = B + (size_t)(n0 + 64 + srow) * K + scol;
    char* la0 = (char*)As + (w << 10);
    char* la1 = (char*)As + 4096 + (w << 10);
    char* lb0 = (char*)Bs + (w << 10);
    char* lb1 = (char*)Bs + 4096 + (w << 10);

    // fragment read positions (A-layout: m=lane&15, k=quad*8+j)
    const int wm = (w >> 1) << 6;    // wave m-offset in tile: 0/64
    const int wn = (w & 1) << 6;     // wave n-offset: 0/64
    const int fr = l & 15;
    const int fq = (l >> 4) << 3;

    floatx4 acc[4][4] = {};

    for (int k0 = 0; k0 < K; k0 += 32) {
        __syncthreads();   // all waves done reading LDS from previous step
        gld_lds16(ga0, la0); gld_lds16(ga1, la1);
        gld_lds16(gb0, lb0); gld_lds16(gb1, lb1);
        ga0 += 32; ga1 += 32; gb0 += 32; gb1 += 32;
        __syncthreads();   // drains vmcnt(0): tiles ready

        bf16x8 a[4], b[4];
        #pragma unroll
        for (int i = 0; i < 4; ++i) {
            a[i] = *(const bf16x8*)&As[(wm + i * 16 + fr) * 32 + fq];
            b[i] = *(const bf16x8*)&Bs[(wn + i * 16 + fr) * 32 + fq];
        }
        #pragma unroll
        for (int i = 0; i < 4; ++i)
            #pragma unroll
            for (int j = 0; j < 4; ++j)
                acc[i][j] = __builtin_amdgcn_mfma_f32_16x16x32_bf16(a[i], b[j], acc[i][j], 0, 0, 0);
    }

    // epilogue: C/D layout col=lane&15 (n), row=(lane>>4)*4+reg (m)
    const int em = m0 + wm + ((l >> 4) << 2);
    const int en = n0 + wn + (l & 15);
    #pragma unroll
    for (int j = 0; j < 4; ++j) {
        const int n = en + j * 16;
        const float bv = ADD_BIAS ? bias[n] : 0.0f;
        #pragma unroll
        for (int i = 0; i < 4; ++i) {
            #pragma unroll
            for (int rg = 0; rg < 4; ++rg)
                C[(size_t)(em + i * 16 + rg) * ldc + n] = (bf16_t)(acc[i][j][rg] + bv);
        }
    }
}

// ---------------------------------------------------------------------------
// output GEMM, 64x64 tile: logits[b,n,m,r] = sum_q hw[b,n,q]*tail[b,m,q] + bil_b[r]
// 4 waves (2x2), each wave 32x32 = 2x2 MFMA tiles. Output fp32, stride-R write.
// ---------------------------------------------------------------------------
__global__ __launch_bounds__(256) void gemm_out_kernel(
    const bf16_t* __restrict__ HW,    // [Mm, Pp] for this r
    const bf16_t* __restrict__ TAIL,  // [Mm, Pp]
    const float*  __restrict__ bil_b,
    float* __restrict__ OUT, int r)
{
    __shared__ bf16_t As[64 * 32];
    __shared__ bf16_t Bs[64 * 32];

    const int b = blockIdx.z;
    const bf16_t* A  = HW   + (size_t)b * Nn * Pp;  // rows n
    const bf16_t* Bt = TAIL + (size_t)b * Nn * Pp;  // rows m

    const int tid = threadIdx.x;
    const int w = tid >> 6;
    const int l = tid & 63;
    const int n0 = blockIdx.y * 64;
    const int m0 = blockIdx.x * 64;

    const int srow = (w << 4) + (l >> 2);
    const int scol = (l & 3) << 3;
    const bf16_t* ga = A  + (size_t)(n0 + srow) * Pp + scol;
    const bf16_t* gb = Bt + (size_t)(m0 + srow) * Pp + scol;
    char* la = (char*)As + (w << 10);
    char* lb = (char*)Bs + (w << 10);

    const int wm = (w >> 1) << 5;   // wave n-offset (rows): 0/32
    const int wn = (w & 1) << 5;    // wave m-offset (cols): 0/32
    const int fr = l & 15;
    const int fq = (l >> 4) << 3;

    floatx4 acc[2][2] = {};

    for (int k0 = 0; k0 < Pp; k0 += 32) {
        __syncthreads();
        gld_lds16(ga, la); gld_lds16(gb, lb);
        ga += 32; gb += 32;
        __syncthreads();

        bf16x8 a[2], bfr[2];
        #pragma unroll
        for (int i = 0; i < 2; ++i) {
            a[i]   = *(const bf16x8*)&As[(wm + i * 16 + fr) * 32 + fq];
            bfr[i] = *(const bf16x8*)&Bs[(wn + i * 16 + fr) * 32 + fq];
        }
        #pragma unroll
        for (int i = 0; i < 2; ++i)
            #pragma unroll
            for (int j = 0; j < 2; ++j)
                acc[i][j] = __builtin_amdgcn_mfma_f32_16x16x32_bf16(a[i], bfr[j], acc[i][j], 0, 0, 0);
    }

    const float bias = bil_b[r];
    const int en_ = n0 + wm + ((l >> 4) << 2);  // output row n
    const int em_ = m0 + wn + (l & 15);         // output col m
    #pragma unroll
    for (int i = 0; i < 2; ++i)
        #pragma unroll
        for (int j = 0; j < 2; ++j)
            #pragma unroll
            for (int rg = 0; rg < 4; ++rg) {
                const int n = en_ + i * 16 + rg;
                const int m = em_ + j * 16;
                OUT[(((size_t)b * Nn + n) * Nn + m) * Rr + r] = acc[i][j][rg] + bias;
            }
}

extern "C" void kernel_launch(void* const* d_in, const int* in_sizes, int n_in,
                              void* d_out, int out_size, void* d_ws, size_t ws_size,
                              hipStream_t stream) {
    const float* features = (const float*)d_in[0]; // [16,256,768]
    const float* head_W   = (const float*)d_in[1]; // [2048,768]
    const float* head_b   = (const float*)d_in[2]; // [2048]
    const float* tail_W   = (const float*)d_in[3]; // [2048,768]
    const float* tail_b   = (const float*)d_in[4]; // [2048]
    const float* bil_W    = (const float*)d_in[5]; // [3,2048,2048]
    const float* bil_b    = (const float*)d_in[6]; // [3]
    float* out = (float*)d_out;                    // [16,256,256,3]

    // workspace layout (bf16), total 88.1 MB
    char* ws = (char*)d_ws;
    bf16_t* fbf     = (bf16_t*)ws;                      ws += (size_t)Mm * Hh * 2;  // 6.3 MB
    bf16_t* hWbf    = (bf16_t*)ws;                      ws += (size_t)Pp * Hh * 2;  // 3.1 MB
    bf16_t* tWbf    = (bf16_t*)ws;                      ws += (size_t)Pp * Hh * 2;  // 3.1 MB
    bf16_t* bilT    = (bf16_t*)ws;                      ws += (size_t)Rr * Pp * Pp * 2; // 25.2 MB
    bf16_t* head_bf = (bf16_t*)ws;                      ws += (size_t)Mm * Pp * 2;  // 16.8 MB
    bf16_t* tail_bf = (bf16_t*)ws;                      ws += (size_t)Mm * Pp * 2;  // 16.8 MB
    bf16_t* hw_bf   = (bf16_t*)ws;                      ws += (size_t)Mm * Pp * 2;  // 16.8 MB

    // 1) dtype conversions
    convert_kernel<<<Mm * Hh / 4 / 256, 256, 0, stream>>>(
        features, head_W, tail_W, fbf, hWbf, tWbf);
    transpose_bilW_kernel<<<dim3(Pp / 32, Pp / 32, Rr), dim3(32, 8), 0, stream>>>(
        bil_W, bilT);

    // 2) projections: head/tail [4096,2048] = fbf [4096,768] @ W^T + b
    gemm_nt_128<Hh, true><<<dim3(Pp / 128, Mm / 128), 256, 0, stream>>>(
        fbf, hWbf, head_b, head_bf, Pp);
    gemm_nt_128<Hh, true><<<dim3(Pp / 128, Mm / 128), 256, 0, stream>>>(
        fbf, tWbf, tail_b, tail_bf, Pp);

    // 3) per relation: hw = head @ bil_W[r]  (NT vs transposed bilT), then output GEMM
    for (int r = 0; r < Rr; ++r) {
        gemm_nt_128<Pp, false><<<dim3(Pp / 128, Mm / 128), 256, 0, stream>>>(
            head_bf, bilT + (size_t)r * Pp * Pp, nullptr, hw_bf, Pp);
        gemm_out_kernel<<<dim3(Nn / 64, Nn / 64, Bb), 256, 0, stream>>>(
            hw_bf, tail_bf, bil_b, out, r);
    }
}

// Round 3
// 276.848 us; speedup vs baseline: 7.3668x; 1.3617x over previous
//
#include <hip/hip_runtime.h>

// Problem constants
constexpr int Bb = 16;      // batch
constexpr int Nn = 256;     // regions
constexpr int Hh = 768;     // hidden
constexpr int Pp = 2048;    // proj dim
constexpr int Rr = 3;       // relation types
constexpr int Mm = Bb * Nn; // 4096 flattened rows
constexpr int RQ = Rr * Pp; // 6144

typedef __bf16 bf16_t;
typedef __bf16 bf16x8 __attribute__((ext_vector_type(8)));
typedef __bf16 bf16x4 __attribute__((ext_vector_type(4)));
typedef float  floatx4 __attribute__((ext_vector_type(4)));

// async global->LDS, 16B per lane; LDS dest = wave-uniform base + lane*16
__device__ __forceinline__ void gld_lds16(const void* g, void* l) {
    __builtin_amdgcn_global_load_lds(
        (__attribute__((address_space(1))) void*)g,
        (__attribute__((address_space(3))) void*)l,
        16, 0, 0);
}

// ---------------------------------------------------------------------------
// convert features / tail_W to bf16 (elementwise, float4-vectorized)
// ---------------------------------------------------------------------------
__global__ __launch_bounds__(256) void convert_kernel(
    const float* __restrict__ f, const float* __restrict__ tW,
    bf16_t* __restrict__ fo, bf16_t* __restrict__ tWo)
{
    const int i = blockIdx.x * 256 + threadIdx.x;
    if (i < Mm * Hh / 4) {
        float4 v = ((const float4*)f)[i];
        bf16x4 o = { (bf16_t)v.x, (bf16_t)v.y, (bf16_t)v.z, (bf16_t)v.w };
        *(bf16x4*)(fo + (size_t)i * 4) = o;
    }
    if (i < Pp * Hh / 4) {
        float4 w = ((const float4*)tW)[i];
        bf16x4 p = { (bf16_t)w.x, (bf16_t)w.y, (bf16_t)w.z, (bf16_t)w.w };
        *(bf16x4*)(tWo + (size_t)i * 4) = p;
    }
}

// ---------------------------------------------------------------------------
// generic 32x32-tiled transpose fp32 -> bf16: src [rows][cols] -> dst [cols][rows]
// grid (cols/32, rows/32), block (32,8)
// ---------------------------------------------------------------------------
__global__ __launch_bounds__(256) void transpose_f32_bf16(
    const float* __restrict__ src, bf16_t* __restrict__ dst, int rows, int cols)
{
    __shared__ float t[32][33];
    const int r0 = blockIdx.y * 32;  // row tile in src
    const int c0 = blockIdx.x * 32;  // col tile in src
    const int tx = threadIdx.x, ty = threadIdx.y;
    #pragma unroll
    for (int s = 0; s < 4; ++s)
        t[ty + s * 8][tx] = src[(size_t)(r0 + ty + s * 8) * cols + c0 + tx];
    __syncthreads();
    #pragma unroll
    for (int s = 0; s < 4; ++s)
        dst[(size_t)(c0 + ty + s * 8) * rows + r0 + tx] = (bf16_t)t[tx][ty + s * 8];
}

// ---------------------------------------------------------------------------
// bil_W [r][p][q] fp32 -> bilT [rq][p] bf16, and b2[rq] += sum_p bh[p]*bil[r][p][q]
// grid (Pp/32, Pp/32, Rr), block (32,8). b2 must be zeroed before launch.
// ---------------------------------------------------------------------------
__global__ __launch_bounds__(256) void transpose_bilW_kernel(
    const float* __restrict__ W, const float* __restrict__ bh,
    bf16_t* __restrict__ Wt, float* __restrict__ b2)
{
    __shared__ float t[32][33];
    const int r  = blockIdx.z;
    const int p0 = blockIdx.y * 32;
    const int q0 = blockIdx.x * 32;
    const int tx = threadIdx.x, ty = threadIdx.y;
    const float* src = W  + (size_t)r * Pp * Pp;
    bf16_t*      dst = Wt + (size_t)r * Pp * Pp;
    #pragma unroll
    for (int s = 0; s < 4; ++s)
        t[ty + s * 8][tx] = src[(size_t)(p0 + ty + s * 8) * Pp + q0 + tx];
    __syncthreads();
    #pragma unroll
    for (int s = 0; s < 4; ++s)
        dst[(size_t)(q0 + ty + s * 8) * Pp + p0 + tx] = (bf16_t)t[tx][ty + s * 8];
    if (ty == 0) {
        float s = 0.0f;
        #pragma unroll 8
        for (int pi = 0; pi < 32; ++pi)
            s += bh[p0 + pi] * t[pi][tx];
        atomicAdd(&b2[r * Pp + q0 + tx], s);
    }
}

// ---------------------------------------------------------------------------
// 128x128-tile bf16 NT GEMM (m97 structure):
//   C[m,n] = sum_k A[m,k]*B[n,k] (+ bias[n]),  C stored bf16
// 256 threads = 4 waves (2x2), each wave 64x64 = 4x4 MFMA 16x16x32 tiles.
// Row stride of A and B is K.
// ---------------------------------------------------------------------------
template <int K, bool ADD_BIAS>
__global__ __launch_bounds__(256) void gemm_nt_128(
    const bf16_t* __restrict__ A,   // [gridDim.y*128, K]
    const bf16_t* __restrict__ B,   // [gridDim.x*128, K]
    const float*  __restrict__ bias,
    bf16_t* __restrict__ C, int ldc)
{
    __shared__ bf16_t As[128 * 32];
    __shared__ bf16_t Bs[128 * 32];

    const int tid = threadIdx.x;
    const int w = tid >> 6;
    const int l = tid & 63;
    const int m0 = blockIdx.y * 128;
    const int n0 = blockIdx.x * 128;

    const int srow = (w << 4) + (l >> 2);
    const int scol = (l & 3) << 3;
    const bf16_t* ga0 = A + (size_t)(m0 +      srow) * K + scol;
    const bf16_t* ga1 = A + (size_t)(m0 + 64 + srow) * K + scol;
    const bf16_t* gb0 = B + (size_t)(n0 +      srow) * K + scol;
    const bf16_t* gb1 = B + (size_t)(n0 + 64 + srow) * K + scol;
    char* la0 = (char*)As + (w << 10);
    char* la1 = (char*)As + 4096 + (w << 10);
    char* lb0 = (char*)Bs + (w << 10);
    char* lb1 = (char*)Bs + 4096 + (w << 10);

    const int wm = (w >> 1) << 6;
    const int wn = (w & 1) << 6;
    const int fr = l & 15;
    const int fq = (l >> 4) << 3;

    floatx4 acc[4][4] = {};

    for (int k0 = 0; k0 < K; k0 += 32) {
        __syncthreads();
        gld_lds16(ga0, la0); gld_lds16(ga1, la1);
        gld_lds16(gb0, lb0); gld_lds16(gb1, lb1);
        ga0 += 32; ga1 += 32; gb0 += 32; gb1 += 32;
        __syncthreads();

        bf16x8 a[4], b[4];
        #pragma unroll
        for (int i = 0; i < 4; ++i) {
            a[i] = *(const bf16x8*)&As[(wm + i * 16 + fr) * 32 + fq];
            b[i] = *(const bf16x8*)&Bs[(wn + i * 16 + fr) * 32 + fq];
        }
        #pragma unroll
        for (int i = 0; i < 4; ++i)
            #pragma unroll
            for (int j = 0; j < 4; ++j)
                acc[i][j] = __builtin_amdgcn_mfma_f32_16x16x32_bf16(a[i], b[j], acc[i][j], 0, 0, 0);
    }

    const int em = m0 + wm + ((l >> 4) << 2);
    const int en = n0 + wn + (l & 15);
    #pragma unroll
    for (int j = 0; j < 4; ++j) {
        const int n = en + j * 16;
        const float bv = ADD_BIAS ? bias[n] : 0.0f;
        #pragma unroll
        for (int i = 0; i < 4; ++i) {
            #pragma unroll
            for (int rg = 0; rg < 4; ++rg)
                C[(size_t)(em + i * 16 + rg) * ldc + n] = (bf16_t)(acc[i][j][rg] + bv);
        }
    }
}

// ---------------------------------------------------------------------------
// fused output GEMM, all 3 r per block, double-buffered LDS:
//   logits[b,n,m,r] = sum_q hw_all[b*Nn+n, r*Pp+q] * tail[b*Nn+m, q] + bil_b[r]
// grid (Nn/64, Nn/64, Bb) = 256 blocks; 4 waves (2x2 over n,m), wave = 32x32.
// ---------------------------------------------------------------------------
__global__ __launch_bounds__(256) void gemm_out_fused(
    const bf16_t* __restrict__ HW,    // [Mm, RQ]
    const bf16_t* __restrict__ TAIL,  // [Mm, Pp]
    const float*  __restrict__ bil_b,
    float* __restrict__ OUT)
{
    // S[buf][tile][64*32]; tiles 0..2 = hw r, 3 = tail
    __shared__ bf16_t S[2][4][64 * 32];

    const int b = blockIdx.z;
    const int n0 = blockIdx.y * 64;
    const int m0 = blockIdx.x * 64;

    const int tid = threadIdx.x;
    const int w = tid >> 6;
    const int l = tid & 63;

    const int srow = (w << 4) + (l >> 2);   // = tid/4
    const int scol = (l & 3) << 3;          // = (tid&3)*8

    const bf16_t* gh[Rr];
    #pragma unroll
    for (int r = 0; r < Rr; ++r)
        gh[r] = HW + (size_t)(b * Nn + n0 + srow) * RQ + r * Pp + scol;
    const bf16_t* gt = TAIL + (size_t)(b * Nn + m0 + srow) * Pp + scol;

    const int wn_ = (w >> 1) << 5;  // wave n-offset: 0/32
    const int wm_ = (w & 1) << 5;   // wave m-offset: 0/32
    const int fr = l & 15;
    const int fq = (l >> 4) << 3;

    floatx4 acc[Rr][2][2] = {};

    // prefetch step 0 into buf 0
    {
        char* base = (char*)&S[0][0][0] + (w << 10);
        #pragma unroll
        for (int r = 0; r < Rr; ++r) { gld_lds16(gh[r], base + r * 4096); gh[r] += 32; }
        gld_lds16(gt, base + 3 * 4096); gt += 32;
    }

    constexpr int STEPS = Pp / 32; // 64
    for (int k = 0; k < STEPS; ++k) {
        __syncthreads();  // drains vmcnt(0): buf[k&1] ready; prev reads of buf[1-k&1] done
        const int cur = k & 1;
        if (k + 1 < STEPS) {
            char* base = (char*)&S[cur ^ 1][0][0] + (w << 10);
            #pragma unroll
            for (int r = 0; r < Rr; ++r) { gld_lds16(gh[r], base + r * 4096); gh[r] += 32; }
            gld_lds16(gt, base + 3 * 4096); gt += 32;
        }

        bf16x8 t[2];
        #pragma unroll
        for (int j = 0; j < 2; ++j)
            t[j] = *(const bf16x8*)&S[cur][3][(wm_ + j * 16 + fr) * 32 + fq];
        #pragma unroll
        for (int r = 0; r < Rr; ++r) {
            bf16x8 a[2];
            #pragma unroll
            for (int i = 0; i < 2; ++i)
                a[i] = *(const bf16x8*)&S[cur][r][(wn_ + i * 16 + fr) * 32 + fq];
            #pragma unroll
            for (int i = 0; i < 2; ++i)
                #pragma unroll
                for (int j = 0; j < 2; ++j)
                    acc[r][i][j] = __builtin_amdgcn_mfma_f32_16x16x32_bf16(a[i], t[j], acc[r][i][j], 0, 0, 0);
        }
    }

    float bb[Rr] = { bil_b[0], bil_b[1], bil_b[2] };
    const int en_ = n0 + wn_ + ((l >> 4) << 2);
    const int em_ = m0 + wm_ + (l & 15);
    #pragma unroll
    for (int i = 0; i < 2; ++i)
        #pragma unroll
        for (int rg = 0; rg < 4; ++rg) {
            const int n = en_ + i * 16 + rg;
            #pragma unroll
            for (int j = 0; j < 2; ++j) {
                const int m = em_ + j * 16;
                float* o = OUT + (((size_t)b * Nn + n) * Nn + m) * Rr;
                #pragma unroll
                for (int r = 0; r < Rr; ++r)
                    o[r] = acc[r][i][j][rg] + bb[r];
            }
        }
}

extern "C" void kernel_launch(void* const* d_in, const int* in_sizes, int n_in,
                              void* d_out, int out_size, void* d_ws, size_t ws_size,
                              hipStream_t stream) {
    const float* features = (const float*)d_in[0]; // [16,256,768]
    const float* head_W   = (const float*)d_in[1]; // [2048,768]
    const float* head_b   = (const float*)d_in[2]; // [2048]
    const float* tail_W   = (const float*)d_in[3]; // [2048,768]
    const float* tail_b   = (const float*)d_in[4]; // [2048]
    const float* bil_W    = (const float*)d_in[5]; // [3,2048,2048]
    const float* bil_b    = (const float*)d_in[6]; // [3]
    float* out = (float*)d_out;                    // [16,256,256,3]

    // workspace layout (~89 MB; hw_all overlays bilT which is dead by then)
    char* ws = (char*)d_ws;
    bf16_t* fbf     = (bf16_t*)ws;  ws += (size_t)Mm * Hh * 2;      // 6.3 MB
    bf16_t* tWbf    = (bf16_t*)ws;  ws += (size_t)Pp * Hh * 2;      // 3.1 MB
    bf16_t* hWT     = (bf16_t*)ws;  ws += (size_t)Hh * Pp * 2;      // 3.1 MB
    bf16_t* W2T     = (bf16_t*)ws;  ws += (size_t)RQ * Hh * 2;      // 9.4 MB
    float*  b2      = (float*)ws;   ws += (size_t)RQ * 4;           // 24 KB
    bf16_t* tail_bf = (bf16_t*)ws;  ws += (size_t)Mm * Pp * 2;      // 16.8 MB
    bf16_t* bilT    = (bf16_t*)ws;                                  // 25.2 MB
    bf16_t* hw_all  = (bf16_t*)ws;  ws += (size_t)Mm * RQ * 2;      // 50.3 MB (overlays bilT)

    // 0) zero b2 (ws is poisoned before every call)
    hipMemsetAsync(b2, 0, (size_t)RQ * sizeof(float), stream);

    // 1) dtype conversions / transposes
    convert_kernel<<<Mm * Hh / 4 / 256, 256, 0, stream>>>(features, tail_W, fbf, tWbf);
    transpose_f32_bf16<<<dim3(Hh / 32, Pp / 32), dim3(32, 8), 0, stream>>>(
        head_W, hWT, Pp, Hh);                           // hWT [768, 2048]
    transpose_bilW_kernel<<<dim3(Pp / 32, Pp / 32, Rr), dim3(32, 8), 0, stream>>>(
        bil_W, head_b, bilT, b2);                       // bilT [6144, 2048], b2 [6144]

    // 2) tail projection: tail_bf [4096,2048] = fbf @ tWbf^T + tail_b
    gemm_nt_128<Hh, true><<<dim3(Pp / 128, Mm / 128), 256, 0, stream>>>(
        fbf, tWbf, tail_b, tail_bf, Pp);

    // 3) W2T [6144, 768] = bilT [6144,2048] @ hWT^T [768,2048]
    gemm_nt_128<Pp, false><<<dim3(Hh / 128, RQ / 128), 256, 0, stream>>>(
        bilT, hWT, nullptr, W2T, Hh);

    // 4) hw_all [4096, 6144] = fbf [4096,768] @ W2T^T + b2
    gemm_nt_128<Hh, true><<<dim3(RQ / 128, Mm / 128), 256, 0, stream>>>(
        fbf, W2T, b2, hw_all, RQ);

    // 5) fused output GEMM over all r
    gemm_out_fused<<<dim3(Nn / 64, Nn / 64, Bb), 256, 0, stream>>>(
        hw_all, tail_bf, bil_b, out);
}